// Round 4
// baseline (294.477 us; speedup 1.0000x reference)
//
#include <hip/hip_runtime.h>

#define N_NODES 50000
#define N_EDGES 1600000
#define NPB     16
#define NCHAIN  16    // sub-chains per node: chain = e & 15
#define KSTR    168   // A-tile k-stride in shorts (160 + 8 pad: breaks bank conflict on A-frag ds_read_b128)
#define EPSV    1e-8f

typedef float f32x4 __attribute__((ext_vector_type(4)));
typedef short s16x8 __attribute__((ext_vector_type(8)));

// 4-aligned 16B chunk for the frames gather (frames rows are 36B, only 4B-aligned)
struct f4u { float a, b, c, d; };

__device__ __forceinline__ float sigmoidf_(float x) { return 1.0f / (1.0f + __expf(-x)); }
// f32 -> bf16 bits, round-to-nearest-even
__device__ __forceinline__ short f2bf(float x) {
    unsigned u = __float_as_uint(x);
    unsigned r = (u + 0x7FFFu + ((u >> 16) & 1u)) >> 16;
    return (short)r;
}
__device__ __forceinline__ float bf2f(short h) {
    return __uint_as_float(((unsigned)(unsigned short)h) << 16);
}

// ---------------------------------------------------------------------------
// Init kernel: head[] = -1  AND  Dekker-split W_so into TRANSPOSED bf16 hi/lo
// WT[o][k] (k-contiguous so each MFMA B-frag is one 16B load), k>=153 zeroed.
// ---------------------------------------------------------------------------
__global__ __launch_bounds__(256) void init_kernel(
    const float* __restrict__ W_so, short* __restrict__ WThi, short* __restrict__ WTlo,
    int* __restrict__ head) {
    int i = blockIdx.x * 256 + threadIdx.x;
    if (i < 128 * 160) {               // i = o*160 + k
        int o = i / 160, k = i - o * 160;
        float w = (k < 153) ? W_so[k * 128 + o] : 0.0f;
        short hh = f2bf(w);
        WThi[i] = hh;
        WTlo[i] = f2bf(w - bf2f(hh));
    }
    if (i < N_NODES * NCHAIN) head[i] = -1;
}

// ---------------------------------------------------------------------------
// Kernel 1: 16-way linked-list bucketing. 1 atomicExch + 1 coalesced store
// per edge = minimal fabric ops for a data-dependent scatter.
// ---------------------------------------------------------------------------
__global__ __launch_bounds__(256) void bucket_kernel(
    const int* __restrict__ row,
    int* __restrict__ head,
    int* __restrict__ nxt) {
    int e = blockIdx.x * 256 + threadIdx.x;
    if (e >= N_EDGES) return;
    int r = row[e];
    int prev = atomicExch(&head[r * NCHAIN + (e & (NCHAIN - 1))], e);
    nxt[e] = prev;
}

// ---------------------------------------------------------------------------
// Kernel 2: all per-node algebra. 16 nodes per 256-thread block.
// Register diet for real 8-blocks/CU occupancy (r2 proved schedulable, r3
// proved default-bounds regalloc blocks it):
//  - merged A is produced DIRECTLY as bf16 hi/lo in LDS (AL) -> K-loop has
//    zero conversions, 2 ds_read_b128 per kk
//  - W transposed to [o][k] -> each B-frag = one 16B global load (L2-hot)
//  - sigL overlays AL after the K-loop (barrier-guarded)
// (256,8) is safe now: max live ~50 regs, no spill expected (WRITE_SIZE is
// the tripwire).
// ---------------------------------------------------------------------------
__global__ __launch_bounds__(256, 8) void node_kernel(
    const float* __restrict__ s,
    const float* __restrict__ v,
    const float* __restrict__ frames,
    const float* __restrict__ W_vd,
    const float* __restrict__ W_vdf,
    const short* __restrict__ WThi,
    const short* __restrict__ WTlo,
    const float* __restrict__ b_so,
    const float* __restrict__ W_vu,
    const float* __restrict__ W_vosf,
    const float* __restrict__ b_vosf,
    const float* __restrict__ W_vuf,
    const int* __restrict__ head,
    const int* __restrict__ nxt,
    float* __restrict__ out0,
    float* __restrict__ out1)
{
    // AL[0]=A hi, AL[1]=A lo, rows k-strided by KSTR shorts. 10.75 KB.
    // After the K-loop barrier it is dead and sigL[16][128] (8 KB) overlays it.
    __shared__ __align__(16) short AL[2][NPB][KSTR];
    __shared__ float vL[NPB][48];
    __shared__ float vhL[NPB][3][16];
    __shared__ float FbarL[NPB][9];
    __shared__ float vdfL[NPB][9];
    __shared__ float gateL[NPB][12];

    float (*sigL)[128] = (float (*)[128])&AL[0][0][0];

    const int t = threadIdx.x;
    const int base = blockIdx.x * NPB;
    const int nn = t >> 4, h = t & 15;
    const int n = base + nn;

    // ---- phase 0: issue head load first (latency overlaps staging), stage
    //      v, s(->bf16 hi/lo); 256 walkers traverse the 16 sub-chains ----
    int e = head[(size_t)n * NCHAIN + h];

#pragma unroll
    for (int r = 0; r < 3; r++) vL[nn][h * 3 + r] = v[(size_t)n * 48 + h * 3 + r];
    {
        const float4* sp4 = (const float4*)(s + (size_t)n * 128 + h * 8);
        float4 s0 = sp4[0], s1 = sp4[1];
        float sv[8] = {s0.x, s0.y, s0.z, s0.w, s1.x, s1.y, s1.z, s1.w};
        s16x8 shi, slo;
#pragma unroll
        for (int j = 0; j < 8; j++) {
            short hh = f2bf(sv[j]);
            shi[j] = hh;
            slo[j] = f2bf(sv[j] - bf2f(hh));
        }
        *(s16x8*)&AL[0][nn][h * 8] = shi;
        *(s16x8*)&AL[1][nn][h * 8] = slo;
    }

    {
        float fs[10];
#pragma unroll
        for (int k = 0; k < 10; k++) fs[k] = 0.f;
        while (e >= 0) {
            int en = nxt[e];  // dependent load issues first; frame loads overlap it
            const float* f = frames + (size_t)e * 9;
            const f4u* fp = (const f4u*)f;
            f4u x = fp[0];
            f4u y = fp[1];
            float z8 = f[8];
            fs[0] += x.a; fs[1] += x.b; fs[2] += x.c; fs[3] += x.d;
            fs[4] += y.a; fs[5] += y.b; fs[6] += y.c; fs[7] += y.d;
            fs[8] += z8;
            fs[9] += 1.0f;
            e = en;
        }
        // butterfly across the node's 16 lanes (contiguous within the wave)
#pragma unroll
        for (int m = 1; m < 16; m <<= 1) {
#pragma unroll
            for (int k = 0; k < 10; k++) fs[k] += __shfl_xor(fs[k], m);
        }
        if (h < 9) {
            float inv = 1.0f / fmaxf(fs[9], 1.0f);
            FbarL[nn][h] = fs[h] * inv;
        }
    }
    __syncthreads();

    // ---- phase 1b: vh, vnorm(->A[128+h]), vdf ----
    {
        float vh0 = 0.f, vh1 = 0.f, vh2 = 0.f;
#pragma unroll
        for (int i = 0; i < 16; i++) {
            float w = W_vd[i * 16 + h];
            vh0 += vL[nn][i * 3 + 0] * w;
            vh1 += vL[nn][i * 3 + 1] * w;
            vh2 += vL[nn][i * 3 + 2] * w;
        }
        vhL[nn][0][h] = vh0; vhL[nn][1][h] = vh1; vhL[nn][2][h] = vh2;
        float vn = sqrtf(vh0 * vh0 + vh1 * vh1 + vh2 * vh2 + EPSV);
        short hh = f2bf(vn);
        AL[0][nn][128 + h] = hh;
        AL[1][nn][128 + h] = f2bf(vn - bf2f(hh));
        if (h < 3) {
            int cc = h;
#pragma unroll
            for (int j = 0; j < 3; j++) {
                float a = 0.f;
#pragma unroll
                for (int i = 0; i < 16; i++) a += vL[nn][i * 3 + j] * W_vdf[i * 3 + cc];
                vdfL[nn][j * 3 + cc] = a;
            }
        }
    }
    __syncthreads();

    // ---- phase 1c: sh(->A[144..152]) + zero A[153..159] ----
    {
        if (h < 9) {
            int c = h / 3, i = h % 3;
            float a = 0.f;
#pragma unroll
            for (int j = 0; j < 3; j++) a += FbarL[nn][i * 3 + j] * vdfL[nn][j * 3 + c];
            short hh = f2bf(a);
            AL[0][nn][144 + h] = hh;
            AL[1][nn][144 + h] = f2bf(a - bf2f(hh));
        } else {
            AL[0][nn][144 + h] = 0;  // k = 153..159
            AL[1][nn][144 + h] = 0;
        }
    }
    __syncthreads();

    // ---- phase 2: C[16x128] = merged[16x160] @ W_so via split-bf16 MFMA ----
    // wave w handles o in [32w, 32w+32): two 16x16 tiles, K-loop 5x32.
    // A-frag: A[m=lane&15][k=quad*8+j] (ds_read_b128 from AL);
    // B-frag: B[k=quad*8+j][n=lane&15] (one b128 from WT[o][k] each);
    // C/D: col=lane&15, row=quad*4+reg (m89/m91/m120-verified layouts).
    {
        const int w = t >> 6;
        const int lane = t & 63;
        const int quad = lane >> 4;
        const int col = lane & 15;
        const int o0 = w * 32 + col, o1 = o0 + 16;
        f32x4 acc0 = (f32x4){0.f, 0.f, 0.f, 0.f};
        f32x4 acc1 = (f32x4){0.f, 0.f, 0.f, 0.f};
#pragma unroll
        for (int kk = 0; kk < 5; kk++) {
            const int krow = kk * 32 + quad * 8;
            s16x8 ahi = *(const s16x8*)&AL[0][col][krow];
            s16x8 alo = *(const s16x8*)&AL[1][col][krow];
            s16x8 b0h = *(const s16x8*)&WThi[o0 * 160 + krow];
            s16x8 b0l = *(const s16x8*)&WTlo[o0 * 160 + krow];
            s16x8 b1h = *(const s16x8*)&WThi[o1 * 160 + krow];
            s16x8 b1l = *(const s16x8*)&WTlo[o1 * 160 + krow];
            acc0 = __builtin_amdgcn_mfma_f32_16x16x32_bf16(ahi, b0h, acc0, 0, 0, 0);
            acc0 = __builtin_amdgcn_mfma_f32_16x16x32_bf16(ahi, b0l, acc0, 0, 0, 0);
            acc0 = __builtin_amdgcn_mfma_f32_16x16x32_bf16(alo, b0h, acc0, 0, 0, 0);
            acc1 = __builtin_amdgcn_mfma_f32_16x16x32_bf16(ahi, b1h, acc1, 0, 0, 0);
            acc1 = __builtin_amdgcn_mfma_f32_16x16x32_bf16(ahi, b1l, acc1, 0, 0, 0);
            acc1 = __builtin_amdgcn_mfma_f32_16x16x32_bf16(alo, b1h, acc1, 0, 0, 0);
        }
        __syncthreads();  // all A-frag reads of AL done -> safe to overlay sigL
        // epilogue: bias, relu -> out0, sigmoid -> sigL (overlaid on AL)
        {
            float b0 = b_so[o0], b1 = b_so[o1];
#pragma unroll
            for (int r = 0; r < 4; r++) {
                int nl = quad * 4 + r;
                float v0 = acc0[r] + b0;
                float v1 = acc1[r] + b1;
                out0[(size_t)(base + nl) * 128 + o0] = fmaxf(v0, 0.0f);
                out0[(size_t)(base + nl) * 128 + o1] = fmaxf(v1, 0.0f);
                sigL[nl][o0] = sigmoidf_(v0);
                sigL[nl][o1] = sigmoidf_(v1);
            }
        }
    }
    __syncthreads();

    // ---- gate = sigmoid(sr) @ W_vosf + b_vosf : partials + shfl butterfly ----
    {
        const float* sp = &sigL[nn][h * 8];
        float4 s0 = *(const float4*)sp;
        float4 s1 = *(const float4*)(sp + 4);
        float sv[8] = {s0.x, s0.y, s0.z, s0.w, s1.x, s1.y, s1.z, s1.w};
        float p[9];
#pragma unroll
        for (int k = 0; k < 9; k++) p[k] = 0.f;
#pragma unroll
        for (int i = 0; i < 8; i++) {
            int o = h * 8 + i;
#pragma unroll
            for (int k = 0; k < 9; k++) p[k] += sv[i] * W_vosf[o * 9 + k];
        }
#pragma unroll
        for (int m = 1; m < 16; m <<= 1) {
#pragma unroll
            for (int k = 0; k < 9; k++) p[k] += __shfl_xor(p[k], m);
        }
        if (h < 9) gateL[nn][h] = p[h] + b_vosf[h];
    }
    __syncthreads();

    // ---- phase 3: vector path ----
    {
        int o = h;  // VO index
        float gv[9];
#pragma unroll
        for (int i = 0; i < 3; i++)
#pragma unroll
            for (int kk = 0; kk < 3; kk++) {
                float a = 0.f;
#pragma unroll
                for (int j = 0; j < 3; j++) a += gateL[nn][j * 3 + i] * FbarL[nn][j * 3 + kk];
                gv[i * 3 + kk] = a;
            }
        float gvr[3];
#pragma unroll
        for (int kk = 0; kk < 3; kk++) {
            float a = 0.f;
#pragma unroll
            for (int i = 0; i < 3; i++) a += gv[i * 3 + kk] * W_vuf[i * 16 + o];
            gvr[kk] = a;
        }
        float gn2 = sqrtf(gvr[0] * gvr[0] + gvr[1] * gvr[1] + gvr[2] * gvr[2] + EPSV);
        float sg = sigmoidf_(gn2);
#pragma unroll
        for (int c = 0; c < 3; c++) {
            float a = 0.f;
#pragma unroll
            for (int h2 = 0; h2 < 16; h2++) a += vhL[nn][c][h2] * W_vu[h2 * 16 + o];
            out1[(size_t)n * 48 + o * 3 + c] = a * sg;
        }
    }
}

extern "C" void kernel_launch(void* const* d_in, const int* in_sizes, int n_in,
                              void* d_out, int out_size, void* d_ws, size_t ws_size,
                              hipStream_t stream) {
    const float* s      = (const float*)d_in[0];
    const float* v      = (const float*)d_in[1];
    const float* frames = (const float*)d_in[2];
    const float* W_vd   = (const float*)d_in[3];
    const float* W_vdf  = (const float*)d_in[4];
    const float* W_so   = (const float*)d_in[5];
    const float* b_so   = (const float*)d_in[6];
    const float* W_vu   = (const float*)d_in[7];
    const float* W_vosf = (const float*)d_in[8];
    const float* b_vosf = (const float*)d_in[9];
    const float* W_vuf  = (const float*)d_in[10];
    const int* edge_index = (const int*)d_in[11];
    // d_in[12] = node_inputs (assumed truthy, per reference)

    // ws: head[50K*16 int] | next[1.6M int] | WThi[128*160 s16] | WTlo[128*160 s16]
    const size_t head_b = (size_t)N_NODES * NCHAIN * sizeof(int);  // 3.2 MB
    const size_t next_b = (size_t)N_EDGES * sizeof(int);           // 6.4 MB
    int*   head = (int*)d_ws;
    int*   nxt  = (int*)((char*)d_ws + head_b);
    short* WThi = (short*)((char*)d_ws + head_b + next_b);
    short* WTlo = WThi + 128 * 160;
    float* out0 = (float*)d_out;
    float* out1 = out0 + (size_t)N_NODES * 128;

    init_kernel<<<(N_NODES * NCHAIN + 255) / 256, 256, 0, stream>>>(W_so, WThi, WTlo, head);
    bucket_kernel<<<(N_EDGES + 255) / 256, 256, 0, stream>>>(edge_index, head, nxt);
    node_kernel<<<N_NODES / NPB, 256, 0, stream>>>(
        s, v, frames, W_vd, W_vdf, WThi, WTlo, b_so, W_vu, W_vosf, b_vosf, W_vuf,
        head, nxt, out0, out1);
}

// Round 5
// 292.619 us; speedup vs baseline: 1.0063x; 1.0063x over previous
//
#include <hip/hip_runtime.h>

#define N_NODES 50000
#define N_EDGES 1600000
#define NPB     16
#define NCHAIN  16    // sub-chains per node: chain = e & 15
#define KSTR    168   // A-tile k-stride in shorts (160 + 8 pad: breaks bank conflict on A-frag ds_read_b128)
#define EPSV    1e-8f

typedef float f32x4 __attribute__((ext_vector_type(4)));
typedef short s16x8 __attribute__((ext_vector_type(8)));

// 4-aligned 16B chunk for the frames gather (frames rows are 36B, only 4B-aligned)
struct f4u { float a, b, c, d; };

__device__ __forceinline__ float sigmoidf_(float x) { return 1.0f / (1.0f + __expf(-x)); }
// f32 -> bf16 bits, round-to-nearest-even
__device__ __forceinline__ short f2bf(float x) {
    unsigned u = __float_as_uint(x);
    unsigned r = (u + 0x7FFFu + ((u >> 16) & 1u)) >> 16;
    return (short)r;
}
__device__ __forceinline__ float bf2f(short h) {
    return __uint_as_float(((unsigned)(unsigned short)h) << 16);
}

// ---------------------------------------------------------------------------
// Init kernel: head[] = -1  AND  Dekker-split W_so into TRANSPOSED bf16 hi/lo
// WT[o][k] (k-contiguous so each MFMA B-frag is one 16B load), k>=153 zeroed.
// ---------------------------------------------------------------------------
__global__ __launch_bounds__(256) void init_kernel(
    const float* __restrict__ W_so, short* __restrict__ WThi, short* __restrict__ WTlo,
    int* __restrict__ head) {
    int i = blockIdx.x * 256 + threadIdx.x;
    if (i < 128 * 160) {               // i = o*160 + k
        int o = i / 160, k = i - o * 160;
        float w = (k < 153) ? W_so[k * 128 + o] : 0.0f;
        short hh = f2bf(w);
        WThi[i] = hh;
        WTlo[i] = f2bf(w - bf2f(hh));
    }
    if (i < N_NODES * NCHAIN) head[i] = -1;
}

// ---------------------------------------------------------------------------
// Kernel 1 (FAT): 16-way bucketing fused with payload scatter. Per edge:
// 1 atomicExch (random, the minimum) + coalesced frame read (e-linear) +
// coalesced FULL 64B slot write pay[e] = {f0..f8, nxt, pad} (full line ->
// no read-modify-write). The chain pointer rides in the SAME cache line as
// the frame, so the node-side walker fetches ONE random line per hop
// (was ~2.55: nxt line + 36B frame straddling ~1.55 lines).
// ---------------------------------------------------------------------------
__global__ __launch_bounds__(256) void bucket_fat_kernel(
    const int* __restrict__ row,
    const float* __restrict__ frames,
    int* __restrict__ head,
    float* __restrict__ pay) {
    int e = blockIdx.x * 256 + threadIdx.x;
    if (e >= N_EDGES) return;
    int r = row[e];
    int prev = atomicExch(&head[r * NCHAIN + (e & (NCHAIN - 1))], e);
    const float* f = frames + (size_t)e * 9;
    const f4u* fp = (const f4u*)f;
    f4u x = fp[0];
    f4u y = fp[1];
    float z8 = f[8];
    float4* dst = (float4*)(pay + (size_t)e * 16);
    dst[0] = make_float4(x.a, x.b, x.c, x.d);
    dst[1] = make_float4(y.a, y.b, y.c, y.d);
    dst[2] = make_float4(z8, __int_as_float(prev), 0.0f, 0.0f);
    dst[3] = make_float4(0.0f, 0.0f, 0.0f, 0.0f);  // full-line write
}

// Thin fallback (ws too small): classic separate-nxt bucketing.
__global__ __launch_bounds__(256) void bucket_thin_kernel(
    const int* __restrict__ row,
    int* __restrict__ head,
    int* __restrict__ nxt) {
    int e = blockIdx.x * 256 + threadIdx.x;
    if (e >= N_EDGES) return;
    int r = row[e];
    int prev = atomicExch(&head[r * NCHAIN + (e & (NCHAIN - 1))], e);
    nxt[e] = prev;
}

// ---------------------------------------------------------------------------
// Kernel 2: all per-node algebra. 16 nodes per 256-thread block.
// FAT=1: walker reads one 64B payload line per hop (frame+nxt together).
// FAT=0: r4-style thin walk (nxt array + raw frames).
// Default launch bounds: the (256,8) clamp spilled twice (r2 +47MB, r4
// +15MB writes); occupancy is NOT the lever for this kernel (39% vs 74%
// gave equal-or-worse time) -> prefer spill-free codegen.
// ---------------------------------------------------------------------------
template<int FAT>
__global__ __launch_bounds__(256) void node_kernel(
    const float* __restrict__ s,
    const float* __restrict__ v,
    const float* __restrict__ fr,      // FAT ? pay[E*16] : frames[E*9]
    const float* __restrict__ W_vd,
    const float* __restrict__ W_vdf,
    const short* __restrict__ WThi,
    const short* __restrict__ WTlo,
    const float* __restrict__ b_so,
    const float* __restrict__ W_vu,
    const float* __restrict__ W_vosf,
    const float* __restrict__ b_vosf,
    const float* __restrict__ W_vuf,
    const int* __restrict__ head,
    const int* __restrict__ nxt,       // used only when FAT=0
    float* __restrict__ out0,
    float* __restrict__ out1)
{
    // AL[0]=A hi, AL[1]=A lo, rows k-strided by KSTR shorts. 10.75 KB.
    // After the K-loop barrier it is dead and sigL[16][128] (8 KB) overlays it.
    __shared__ __align__(16) short AL[2][NPB][KSTR];
    __shared__ float vL[NPB][48];
    __shared__ float vhL[NPB][3][16];
    __shared__ float FbarL[NPB][9];
    __shared__ float vdfL[NPB][9];
    __shared__ float gateL[NPB][12];

    float (*sigL)[128] = (float (*)[128])&AL[0][0][0];

    const int t = threadIdx.x;
    const int base = blockIdx.x * NPB;
    const int nn = t >> 4, h = t & 15;
    const int n = base + nn;

    // ---- phase 0: issue head load first (latency overlaps staging), stage
    //      v, s(->bf16 hi/lo); 256 walkers traverse the 16 sub-chains ----
    int e = head[(size_t)n * NCHAIN + h];

#pragma unroll
    for (int r = 0; r < 3; r++) vL[nn][h * 3 + r] = v[(size_t)n * 48 + h * 3 + r];
    {
        const float4* sp4 = (const float4*)(s + (size_t)n * 128 + h * 8);
        float4 s0 = sp4[0], s1 = sp4[1];
        float sv[8] = {s0.x, s0.y, s0.z, s0.w, s1.x, s1.y, s1.z, s1.w};
        s16x8 shi, slo;
#pragma unroll
        for (int j = 0; j < 8; j++) {
            short hh = f2bf(sv[j]);
            shi[j] = hh;
            slo[j] = f2bf(sv[j] - bf2f(hh));
        }
        *(s16x8*)&AL[0][nn][h * 8] = shi;
        *(s16x8*)&AL[1][nn][h * 8] = slo;
    }

    {
        float fs[10];
#pragma unroll
        for (int k = 0; k < 10; k++) fs[k] = 0.f;
        if (FAT) {
            while (e >= 0) {
                const float4* p = (const float4*)(fr + (size_t)e * 16);
                float4 c2 = p[2];                 // {f8, nxt_bits, 0, 0} - same line
                float4 c0 = p[0];
                float4 c1 = p[1];
                int en = __float_as_int(c2.y);
                fs[0] += c0.x; fs[1] += c0.y; fs[2] += c0.z; fs[3] += c0.w;
                fs[4] += c1.x; fs[5] += c1.y; fs[6] += c1.z; fs[7] += c1.w;
                fs[8] += c2.x;
                fs[9] += 1.0f;
                e = en;
            }
        } else {
            while (e >= 0) {
                int en = nxt[e];
                const float* f = fr + (size_t)e * 9;
                const f4u* fp = (const f4u*)f;
                f4u x = fp[0];
                f4u y = fp[1];
                float z8 = f[8];
                fs[0] += x.a; fs[1] += x.b; fs[2] += x.c; fs[3] += x.d;
                fs[4] += y.a; fs[5] += y.b; fs[6] += y.c; fs[7] += y.d;
                fs[8] += z8;
                fs[9] += 1.0f;
                e = en;
            }
        }
        // butterfly across the node's 16 lanes (contiguous within the wave)
#pragma unroll
        for (int m = 1; m < 16; m <<= 1) {
#pragma unroll
            for (int k = 0; k < 10; k++) fs[k] += __shfl_xor(fs[k], m);
        }
        if (h < 9) {
            float inv = 1.0f / fmaxf(fs[9], 1.0f);
            FbarL[nn][h] = fs[h] * inv;
        }
    }
    __syncthreads();

    // ---- phase 1b: vh, vnorm(->A[128+h]), vdf ----
    {
        float vh0 = 0.f, vh1 = 0.f, vh2 = 0.f;
#pragma unroll
        for (int i = 0; i < 16; i++) {
            float w = W_vd[i * 16 + h];
            vh0 += vL[nn][i * 3 + 0] * w;
            vh1 += vL[nn][i * 3 + 1] * w;
            vh2 += vL[nn][i * 3 + 2] * w;
        }
        vhL[nn][0][h] = vh0; vhL[nn][1][h] = vh1; vhL[nn][2][h] = vh2;
        float vn = sqrtf(vh0 * vh0 + vh1 * vh1 + vh2 * vh2 + EPSV);
        short hh = f2bf(vn);
        AL[0][nn][128 + h] = hh;
        AL[1][nn][128 + h] = f2bf(vn - bf2f(hh));
        if (h < 3) {
            int cc = h;
#pragma unroll
            for (int j = 0; j < 3; j++) {
                float a = 0.f;
#pragma unroll
                for (int i = 0; i < 16; i++) a += vL[nn][i * 3 + j] * W_vdf[i * 3 + cc];
                vdfL[nn][j * 3 + cc] = a;
            }
        }
    }
    __syncthreads();

    // ---- phase 1c: sh(->A[144..152]) + zero A[153..159] ----
    {
        if (h < 9) {
            int c = h / 3, i = h % 3;
            float a = 0.f;
#pragma unroll
            for (int j = 0; j < 3; j++) a += FbarL[nn][i * 3 + j] * vdfL[nn][j * 3 + c];
            short hh = f2bf(a);
            AL[0][nn][144 + h] = hh;
            AL[1][nn][144 + h] = f2bf(a - bf2f(hh));
        } else {
            AL[0][nn][144 + h] = 0;  // k = 153..159
            AL[1][nn][144 + h] = 0;
        }
    }
    __syncthreads();

    // ---- phase 2: C[16x128] = merged[16x160] @ W_so via split-bf16 MFMA ----
    // wave w handles o in [32w, 32w+32): two 16x16 tiles, K-loop 5x32.
    // A-frag: A[m=lane&15][k=quad*8+j] (ds_read_b128 from AL);
    // B-frag: B[k=quad*8+j][n=lane&15] (one b128 from WT[o][k] each);
    // C/D: col=lane&15, row=quad*4+reg (m89/m91/m120-verified layouts).
    {
        const int w = t >> 6;
        const int lane = t & 63;
        const int quad = lane >> 4;
        const int col = lane & 15;
        const int o0 = w * 32 + col, o1 = o0 + 16;
        f32x4 acc0 = (f32x4){0.f, 0.f, 0.f, 0.f};
        f32x4 acc1 = (f32x4){0.f, 0.f, 0.f, 0.f};
#pragma unroll
        for (int kk = 0; kk < 5; kk++) {
            const int krow = kk * 32 + quad * 8;
            s16x8 ahi = *(const s16x8*)&AL[0][col][krow];
            s16x8 alo = *(const s16x8*)&AL[1][col][krow];
            s16x8 b0h = *(const s16x8*)&WThi[o0 * 160 + krow];
            s16x8 b0l = *(const s16x8*)&WTlo[o0 * 160 + krow];
            s16x8 b1h = *(const s16x8*)&WThi[o1 * 160 + krow];
            s16x8 b1l = *(const s16x8*)&WTlo[o1 * 160 + krow];
            acc0 = __builtin_amdgcn_mfma_f32_16x16x32_bf16(ahi, b0h, acc0, 0, 0, 0);
            acc0 = __builtin_amdgcn_mfma_f32_16x16x32_bf16(ahi, b0l, acc0, 0, 0, 0);
            acc0 = __builtin_amdgcn_mfma_f32_16x16x32_bf16(alo, b0h, acc0, 0, 0, 0);
            acc1 = __builtin_amdgcn_mfma_f32_16x16x32_bf16(ahi, b1h, acc1, 0, 0, 0);
            acc1 = __builtin_amdgcn_mfma_f32_16x16x32_bf16(ahi, b1l, acc1, 0, 0, 0);
            acc1 = __builtin_amdgcn_mfma_f32_16x16x32_bf16(alo, b1h, acc1, 0, 0, 0);
        }
        __syncthreads();  // all A-frag reads of AL done -> safe to overlay sigL
        // epilogue: bias, relu -> out0, sigmoid -> sigL (overlaid on AL)
        {
            float b0 = b_so[o0], b1 = b_so[o1];
#pragma unroll
            for (int r = 0; r < 4; r++) {
                int nl = quad * 4 + r;
                float v0 = acc0[r] + b0;
                float v1 = acc1[r] + b1;
                out0[(size_t)(base + nl) * 128 + o0] = fmaxf(v0, 0.0f);
                out0[(size_t)(base + nl) * 128 + o1] = fmaxf(v1, 0.0f);
                sigL[nl][o0] = sigmoidf_(v0);
                sigL[nl][o1] = sigmoidf_(v1);
            }
        }
    }
    __syncthreads();

    // ---- gate = sigmoid(sr) @ W_vosf + b_vosf : partials + shfl butterfly ----
    {
        const float* sp = &sigL[nn][h * 8];
        float4 s0 = *(const float4*)sp;
        float4 s1 = *(const float4*)(sp + 4);
        float sv[8] = {s0.x, s0.y, s0.z, s0.w, s1.x, s1.y, s1.z, s1.w};
        float p[9];
#pragma unroll
        for (int k = 0; k < 9; k++) p[k] = 0.f;
#pragma unroll
        for (int i = 0; i < 8; i++) {
            int o = h * 8 + i;
#pragma unroll
            for (int k = 0; k < 9; k++) p[k] += sv[i] * W_vosf[o * 9 + k];
        }
#pragma unroll
        for (int m = 1; m < 16; m <<= 1) {
#pragma unroll
            for (int k = 0; k < 9; k++) p[k] += __shfl_xor(p[k], m);
        }
        if (h < 9) gateL[nn][h] = p[h] + b_vosf[h];
    }
    __syncthreads();

    // ---- phase 3: vector path ----
    {
        int o = h;  // VO index
        float gv[9];
#pragma unroll
        for (int i = 0; i < 3; i++)
#pragma unroll
            for (int kk = 0; kk < 3; kk++) {
                float a = 0.f;
#pragma unroll
                for (int j = 0; j < 3; j++) a += gateL[nn][j * 3 + i] * FbarL[nn][j * 3 + kk];
                gv[i * 3 + kk] = a;
            }
        float gvr[3];
#pragma unroll
        for (int kk = 0; kk < 3; kk++) {
            float a = 0.f;
#pragma unroll
            for (int i = 0; i < 3; i++) a += gv[i * 3 + kk] * W_vuf[i * 16 + o];
            gvr[kk] = a;
        }
        float gn2 = sqrtf(gvr[0] * gvr[0] + gvr[1] * gvr[1] + gvr[2] * gvr[2] + EPSV);
        float sg = sigmoidf_(gn2);
#pragma unroll
        for (int c = 0; c < 3; c++) {
            float a = 0.f;
#pragma unroll
            for (int h2 = 0; h2 < 16; h2++) a += vhL[nn][c][h2] * W_vu[h2 * 16 + o];
            out1[(size_t)n * 48 + o * 3 + c] = a * sg;
        }
    }
}

extern "C" void kernel_launch(void* const* d_in, const int* in_sizes, int n_in,
                              void* d_out, int out_size, void* d_ws, size_t ws_size,
                              hipStream_t stream) {
    const float* s      = (const float*)d_in[0];
    const float* v      = (const float*)d_in[1];
    const float* frames = (const float*)d_in[2];
    const float* W_vd   = (const float*)d_in[3];
    const float* W_vdf  = (const float*)d_in[4];
    const float* W_so   = (const float*)d_in[5];
    const float* b_so   = (const float*)d_in[6];
    const float* W_vu   = (const float*)d_in[7];
    const float* W_vosf = (const float*)d_in[8];
    const float* b_vosf = (const float*)d_in[9];
    const float* W_vuf  = (const float*)d_in[10];
    const int* edge_index = (const int*)d_in[11];
    // d_in[12] = node_inputs (assumed truthy, per reference)

    // ws layout: head[50K*16 int] | WThi | WTlo | payload
    //   payload (fat):  pay[E * 16 floats]  (64B-aligned slots, 102.4 MB)
    //   payload (thin): nxt[E int]          (6.4 MB)
    const size_t head_b = (size_t)N_NODES * NCHAIN * sizeof(int);  // 3,200,000 (64B mult)
    const size_t wt_b   = (size_t)128 * 160 * sizeof(short);       // 40,960
    const size_t pay_off = head_b + 2 * wt_b;                      // 3,281,920 (64B mult)
    int*   head = (int*)d_ws;
    short* WThi = (short*)((char*)d_ws + head_b);
    short* WTlo = WThi + 128 * 160;
    float* out0 = (float*)d_out;
    float* out1 = out0 + (size_t)N_NODES * 128;

    const size_t fat_need = pay_off + (size_t)N_EDGES * 64;
    init_kernel<<<(N_NODES * NCHAIN + 255) / 256, 256, 0, stream>>>(W_so, WThi, WTlo, head);

    if (ws_size >= fat_need) {
        float* pay = (float*)((char*)d_ws + pay_off);
        bucket_fat_kernel<<<(N_EDGES + 255) / 256, 256, 0, stream>>>(edge_index, frames, head, pay);
        node_kernel<1><<<N_NODES / NPB, 256, 0, stream>>>(
            s, v, pay, W_vd, W_vdf, WThi, WTlo, b_so, W_vu, W_vosf, b_vosf, W_vuf,
            head, (const int*)nullptr, out0, out1);
    } else {
        int* nxt = (int*)((char*)d_ws + pay_off);
        bucket_thin_kernel<<<(N_EDGES + 255) / 256, 256, 0, stream>>>(edge_index, head, nxt);
        node_kernel<0><<<N_NODES / NPB, 256, 0, stream>>>(
            s, v, frames, W_vd, W_vdf, WThi, WTlo, b_so, W_vu, W_vosf, b_vosf, W_vuf,
            head, nxt, out0, out1);
    }
}

// Round 6
// 279.581 us; speedup vs baseline: 1.0533x; 1.0466x over previous
//
#include <hip/hip_runtime.h>

#define N_NODES 50000
#define N_EDGES 1600000
#define NPB     16
#define NCHAIN  16    // sub-chains per node: chain = e & 15
#define KSTR    168   // A-tile k-stride in shorts (160 + 8 pad: breaks bank conflict on A-frag ds_read_b128)
#define EPSV    1e-8f

typedef float f32x4 __attribute__((ext_vector_type(4)));
typedef short s16x8 __attribute__((ext_vector_type(8)));

// 4-aligned 16B chunk for the frames gather (frames rows are 36B, only 4B-aligned)
struct f4u { float a, b, c, d; };

__device__ __forceinline__ float sigmoidf_(float x) { return 1.0f / (1.0f + __expf(-x)); }
// f32 -> bf16 bits, round-to-nearest-even
__device__ __forceinline__ short f2bf(float x) {
    unsigned u = __float_as_uint(x);
    unsigned r = (u + 0x7FFFu + ((u >> 16) & 1u)) >> 16;
    return (short)r;
}
__device__ __forceinline__ float bf2f(short h) {
    return __uint_as_float(((unsigned)(unsigned short)h) << 16);
}

// ---------------------------------------------------------------------------
// Init kernel: head[] = -1  AND  Dekker-split W_so into TRANSPOSED bf16 hi/lo
// WT[o][k] (k-contiguous so each MFMA B-frag is one 16B load), k>=153 zeroed.
// ---------------------------------------------------------------------------
__global__ __launch_bounds__(256) void init_kernel(
    const float* __restrict__ W_so, short* __restrict__ WThi, short* __restrict__ WTlo,
    int* __restrict__ head) {
    int i = blockIdx.x * 256 + threadIdx.x;
    if (i < 128 * 160) {               // i = o*160 + k
        int o = i / 160, k = i - o * 160;
        float w = (k < 153) ? W_so[k * 128 + o] : 0.0f;
        short hh = f2bf(w);
        WThi[i] = hh;
        WTlo[i] = f2bf(w - bf2f(hh));
    }
    if (i < N_NODES * NCHAIN) head[i] = -1;
}

// ---------------------------------------------------------------------------
// Kernel 1 (FAT): 16-way bucketing fused with payload scatter. Per edge:
// 1 atomicExch (random, the minimum) + coalesced frame read (e-linear) +
// coalesced 48B payload write pay[e] = {f0..f8, nxt} into a 64B-aligned/
// 64B-strided slot (words 12..15 never written nor read: HBM masked-sector
// writes make partial-line streaming writes RMW-free). The chain pointer
// rides in the SAME cache line as the frame -> node walker fetches ONE
// random line per hop.
// A/B this round: -25.6MB writes. If dur ~unchanged, bucket is atomic-
// fabric-bound (1.6M exchanges = floor); if -8us, it's write-BW-bound.
// ---------------------------------------------------------------------------
__global__ __launch_bounds__(256) void bucket_fat_kernel(
    const int* __restrict__ row,
    const float* __restrict__ frames,
    int* __restrict__ head,
    float* __restrict__ pay) {
    int e = blockIdx.x * 256 + threadIdx.x;
    if (e >= N_EDGES) return;
    int r = row[e];
    int prev = atomicExch(&head[r * NCHAIN + (e & (NCHAIN - 1))], e);
    const float* f = frames + (size_t)e * 9;
    const f4u* fp = (const f4u*)f;
    f4u x = fp[0];
    f4u y = fp[1];
    float z8 = f[8];
    float4* dst = (float4*)(pay + (size_t)e * 16);
    dst[0] = make_float4(x.a, x.b, x.c, x.d);
    dst[1] = make_float4(y.a, y.b, y.c, y.d);
    dst[2] = make_float4(z8, __int_as_float(prev), 0.0f, 0.0f);
    // dst[3] intentionally unwritten (never read)
}

// Thin fallback (ws too small): classic separate-nxt bucketing.
__global__ __launch_bounds__(256) void bucket_thin_kernel(
    const int* __restrict__ row,
    int* __restrict__ head,
    int* __restrict__ nxt) {
    int e = blockIdx.x * 256 + threadIdx.x;
    if (e >= N_EDGES) return;
    int r = row[e];
    int prev = atomicExch(&head[r * NCHAIN + (e & (NCHAIN - 1))], e);
    nxt[e] = prev;
}

// ---------------------------------------------------------------------------
// Kernel 2: all per-node algebra. 16 nodes per 256-thread block.
// FAT=1: walker reads one 64B payload line per hop (frame+nxt together).
// FAT=0: thin walk (nxt array + raw frames).
// Phase fusion: after the 16-lane butterfly EVERY lane holds all fs[0..9]
// in registers, so sh can be computed per-lane (vdf recomputed in-lane,
// Fbar from registers) -> vdfL deleted, barriers 7 -> 5.
// Default launch bounds: (256,8) clamp spilled twice (r2 +47MB, r4 +15MB
// writes); occupancy is not the lever for this kernel.
// ---------------------------------------------------------------------------
template<int FAT>
__global__ __launch_bounds__(256) void node_kernel(
    const float* __restrict__ s,
    const float* __restrict__ v,
    const float* __restrict__ fr,      // FAT ? pay[E*16] : frames[E*9]
    const float* __restrict__ W_vd,
    const float* __restrict__ W_vdf,
    const short* __restrict__ WThi,
    const short* __restrict__ WTlo,
    const float* __restrict__ b_so,
    const float* __restrict__ W_vu,
    const float* __restrict__ W_vosf,
    const float* __restrict__ b_vosf,
    const float* __restrict__ W_vuf,
    const int* __restrict__ head,
    const int* __restrict__ nxt,       // used only when FAT=0
    float* __restrict__ out0,
    float* __restrict__ out1)
{
    // AL[0]=A hi, AL[1]=A lo, rows k-strided by KSTR shorts. 10.5 KB.
    // After the K-loop barrier it is dead and sigL[16][128] (8 KB) overlays it.
    __shared__ __align__(16) short AL[2][NPB][KSTR];
    __shared__ float vL[NPB][48];
    __shared__ float vhL[NPB][3][16];
    __shared__ float FbarL[NPB][9];
    __shared__ float gateL[NPB][12];

    float (*sigL)[128] = (float (*)[128])&AL[0][0][0];

    const int t = threadIdx.x;
    const int base = blockIdx.x * NPB;
    const int nn = t >> 4, h = t & 15;
    const int n = base + nn;

    // ---- phase 0: issue head load first (latency overlaps staging), stage
    //      v, s(->bf16 hi/lo); 256 walkers traverse the 16 sub-chains ----
    int e = head[(size_t)n * NCHAIN + h];

#pragma unroll
    for (int r = 0; r < 3; r++) vL[nn][h * 3 + r] = v[(size_t)n * 48 + h * 3 + r];
    {
        const float4* sp4 = (const float4*)(s + (size_t)n * 128 + h * 8);
        float4 s0 = sp4[0], s1 = sp4[1];
        float sv[8] = {s0.x, s0.y, s0.z, s0.w, s1.x, s1.y, s1.z, s1.w};
        s16x8 shi, slo;
#pragma unroll
        for (int j = 0; j < 8; j++) {
            short hh = f2bf(sv[j]);
            shi[j] = hh;
            slo[j] = f2bf(sv[j] - bf2f(hh));
        }
        *(s16x8*)&AL[0][nn][h * 8] = shi;
        *(s16x8*)&AL[1][nn][h * 8] = slo;
    }

    float fs[10];   // after butterfly: ALL lanes hold the node's full sums
#pragma unroll
    for (int k = 0; k < 10; k++) fs[k] = 0.f;
    {
        if (FAT) {
            while (e >= 0) {
                const float4* p = (const float4*)(fr + (size_t)e * 16);
                float4 c2 = p[2];                 // {f8, nxt_bits, -, -} - same line
                float4 c0 = p[0];
                float4 c1 = p[1];
                int en = __float_as_int(c2.y);
                fs[0] += c0.x; fs[1] += c0.y; fs[2] += c0.z; fs[3] += c0.w;
                fs[4] += c1.x; fs[5] += c1.y; fs[6] += c1.z; fs[7] += c1.w;
                fs[8] += c2.x;
                fs[9] += 1.0f;
                e = en;
            }
        } else {
            while (e >= 0) {
                int en = nxt[e];
                const float* f = fr + (size_t)e * 9;
                const f4u* fp = (const f4u*)f;
                f4u x = fp[0];
                f4u y = fp[1];
                float z8 = f[8];
                fs[0] += x.a; fs[1] += x.b; fs[2] += x.c; fs[3] += x.d;
                fs[4] += y.a; fs[5] += y.b; fs[6] += y.c; fs[7] += y.d;
                fs[8] += z8;
                fs[9] += 1.0f;
                e = en;
            }
        }
        // butterfly across the node's 16 lanes (contiguous within the wave)
#pragma unroll
        for (int m = 1; m < 16; m <<= 1) {
#pragma unroll
            for (int k = 0; k < 10; k++) fs[k] += __shfl_xor(fs[k], m);
        }
        if (h < 9) {
            float inv = 1.0f / fmaxf(fs[9], 1.0f);
            FbarL[nn][h] = fs[h] * inv;   // for phase 3 (covered by later barriers)
        }
    }
    __syncthreads();

    // ---- phase 1 (fused): vh, vnorm(->A[128+h]), sh(->A[144..152]) ----
    {
        float vh0 = 0.f, vh1 = 0.f, vh2 = 0.f;
#pragma unroll
        for (int i = 0; i < 16; i++) {
            float w = W_vd[i * 16 + h];
            vh0 += vL[nn][i * 3 + 0] * w;
            vh1 += vL[nn][i * 3 + 1] * w;
            vh2 += vL[nn][i * 3 + 2] * w;
        }
        vhL[nn][0][h] = vh0; vhL[nn][1][h] = vh1; vhL[nn][2][h] = vh2;
        float vn = sqrtf(vh0 * vh0 + vh1 * vh1 + vh2 * vh2 + EPSV);
        short hh = f2bf(vn);
        AL[0][nn][128 + h] = hh;
        AL[1][nn][128 + h] = f2bf(vn - bf2f(hh));
        if (h < 9) {
            // sh[h], h = c*3...: c = h/3 (vdf column), i = h%3 (Fbar row)
            const int c = h / 3, i = h % 3;
            const float inv = 1.0f / fmaxf(fs[9], 1.0f);
            float a = 0.f;
#pragma unroll
            for (int j = 0; j < 3; j++) {
                // vdf[j*3+c] recomputed in-lane (3 dots of 16, vL same-group)
                float vd = 0.f;
#pragma unroll
                for (int ii = 0; ii < 16; ii++) vd += vL[nn][ii * 3 + j] * W_vdf[ii * 3 + c];
                a += (fs[i * 3 + j] * inv) * vd;   // Fbar from registers
            }
            short hs = f2bf(a);
            AL[0][nn][144 + h] = hs;
            AL[1][nn][144 + h] = f2bf(a - bf2f(hs));
        } else {
            AL[0][nn][144 + h] = 0;  // k = 153..159
            AL[1][nn][144 + h] = 0;
        }
    }
    __syncthreads();

    // ---- phase 2: C[16x128] = merged[16x160] @ W_so via split-bf16 MFMA ----
    // wave w handles o in [32w, 32w+32): two 16x16 tiles, K-loop 5x32.
    // A-frag: A[m=lane&15][k=quad*8+j] (ds_read_b128 from AL);
    // B-frag: B[k=quad*8+j][n=lane&15] (one b128 from WT[o][k] each);
    // C/D: col=lane&15, row=quad*4+reg (m89/m91/m120-verified layouts).
    {
        const int w = t >> 6;
        const int lane = t & 63;
        const int quad = lane >> 4;
        const int col = lane & 15;
        const int o0 = w * 32 + col, o1 = o0 + 16;
        f32x4 acc0 = (f32x4){0.f, 0.f, 0.f, 0.f};
        f32x4 acc1 = (f32x4){0.f, 0.f, 0.f, 0.f};
#pragma unroll
        for (int kk = 0; kk < 5; kk++) {
            const int krow = kk * 32 + quad * 8;
            s16x8 ahi = *(const s16x8*)&AL[0][col][krow];
            s16x8 alo = *(const s16x8*)&AL[1][col][krow];
            s16x8 b0h = *(const s16x8*)&WThi[o0 * 160 + krow];
            s16x8 b0l = *(const s16x8*)&WTlo[o0 * 160 + krow];
            s16x8 b1h = *(const s16x8*)&WThi[o1 * 160 + krow];
            s16x8 b1l = *(const s16x8*)&WTlo[o1 * 160 + krow];
            acc0 = __builtin_amdgcn_mfma_f32_16x16x32_bf16(ahi, b0h, acc0, 0, 0, 0);
            acc0 = __builtin_amdgcn_mfma_f32_16x16x32_bf16(ahi, b0l, acc0, 0, 0, 0);
            acc0 = __builtin_amdgcn_mfma_f32_16x16x32_bf16(alo, b0h, acc0, 0, 0, 0);
            acc1 = __builtin_amdgcn_mfma_f32_16x16x32_bf16(ahi, b1h, acc1, 0, 0, 0);
            acc1 = __builtin_amdgcn_mfma_f32_16x16x32_bf16(ahi, b1l, acc1, 0, 0, 0);
            acc1 = __builtin_amdgcn_mfma_f32_16x16x32_bf16(alo, b1h, acc1, 0, 0, 0);
        }
        __syncthreads();  // all A-frag reads of AL done -> safe to overlay sigL
        // epilogue: bias, relu -> out0, sigmoid -> sigL (overlaid on AL)
        {
            float b0 = b_so[o0], b1 = b_so[o1];
#pragma unroll
            for (int r = 0; r < 4; r++) {
                int nl = quad * 4 + r;
                float v0 = acc0[r] + b0;
                float v1 = acc1[r] + b1;
                out0[(size_t)(base + nl) * 128 + o0] = fmaxf(v0, 0.0f);
                out0[(size_t)(base + nl) * 128 + o1] = fmaxf(v1, 0.0f);
                sigL[nl][o0] = sigmoidf_(v0);
                sigL[nl][o1] = sigmoidf_(v1);
            }
        }
    }
    __syncthreads();

    // ---- gate = sigmoid(sr) @ W_vosf + b_vosf : partials + shfl butterfly ----
    {
        const float* sp = &sigL[nn][h * 8];
        float4 s0 = *(const float4*)sp;
        float4 s1 = *(const float4*)(sp + 4);
        float sv[8] = {s0.x, s0.y, s0.z, s0.w, s1.x, s1.y, s1.z, s1.w};
        float p[9];
#pragma unroll
        for (int k = 0; k < 9; k++) p[k] = 0.f;
#pragma unroll
        for (int i = 0; i < 8; i++) {
            int o = h * 8 + i;
#pragma unroll
            for (int k = 0; k < 9; k++) p[k] += sv[i] * W_vosf[o * 9 + k];
        }
#pragma unroll
        for (int m = 1; m < 16; m <<= 1) {
#pragma unroll
            for (int k = 0; k < 9; k++) p[k] += __shfl_xor(p[k], m);
        }
        if (h < 9) gateL[nn][h] = p[h] + b_vosf[h];
    }
    __syncthreads();

    // ---- phase 3: vector path ----
    {
        int o = h;  // VO index
        float gv[9];
#pragma unroll
        for (int i = 0; i < 3; i++)
#pragma unroll
            for (int kk = 0; kk < 3; kk++) {
                float a = 0.f;
#pragma unroll
                for (int j = 0; j < 3; j++) a += gateL[nn][j * 3 + i] * FbarL[nn][j * 3 + kk];
                gv[i * 3 + kk] = a;
            }
        float gvr[3];
#pragma unroll
        for (int kk = 0; kk < 3; kk++) {
            float a = 0.f;
#pragma unroll
            for (int i = 0; i < 3; i++) a += gv[i * 3 + kk] * W_vuf[i * 16 + o];
            gvr[kk] = a;
        }
        float gn2 = sqrtf(gvr[0] * gvr[0] + gvr[1] * gvr[1] + gvr[2] * gvr[2] + EPSV);
        float sg = sigmoidf_(gn2);
#pragma unroll
        for (int c = 0; c < 3; c++) {
            float a = 0.f;
#pragma unroll
            for (int h2 = 0; h2 < 16; h2++) a += vhL[nn][c][h2] * W_vu[h2 * 16 + o];
            out1[(size_t)n * 48 + o * 3 + c] = a * sg;
        }
    }
}

extern "C" void kernel_launch(void* const* d_in, const int* in_sizes, int n_in,
                              void* d_out, int out_size, void* d_ws, size_t ws_size,
                              hipStream_t stream) {
    const float* s      = (const float*)d_in[0];
    const float* v      = (const float*)d_in[1];
    const float* frames = (const float*)d_in[2];
    const float* W_vd   = (const float*)d_in[3];
    const float* W_vdf  = (const float*)d_in[4];
    const float* W_so   = (const float*)d_in[5];
    const float* b_so   = (const float*)d_in[6];
    const float* W_vu   = (const float*)d_in[7];
    const float* W_vosf = (const float*)d_in[8];
    const float* b_vosf = (const float*)d_in[9];
    const float* W_vuf  = (const float*)d_in[10];
    const int* edge_index = (const int*)d_in[11];
    // d_in[12] = node_inputs (assumed truthy, per reference)

    // ws layout: head[50K*16 int] | WThi | WTlo | payload
    //   payload (fat):  pay[E * 16 floats]  (64B-aligned slots, 102.4 MB)
    //   payload (thin): nxt[E int]          (6.4 MB)
    const size_t head_b = (size_t)N_NODES * NCHAIN * sizeof(int);  // 3,200,000 (64B mult)
    const size_t wt_b   = (size_t)128 * 160 * sizeof(short);       // 40,960
    const size_t pay_off = head_b + 2 * wt_b;                      // 3,281,920 (64B mult)
    int*   head = (int*)d_ws;
    short* WThi = (short*)((char*)d_ws + head_b);
    short* WTlo = WThi + 128 * 160;
    float* out0 = (float*)d_out;
    float* out1 = out0 + (size_t)N_NODES * 128;

    const size_t fat_need = pay_off + (size_t)N_EDGES * 64;
    init_kernel<<<(N_NODES * NCHAIN + 255) / 256, 256, 0, stream>>>(W_so, WThi, WTlo, head);

    if (ws_size >= fat_need) {
        float* pay = (float*)((char*)d_ws + pay_off);
        bucket_fat_kernel<<<(N_EDGES + 255) / 256, 256, 0, stream>>>(edge_index, frames, head, pay);
        node_kernel<1><<<N_NODES / NPB, 256, 0, stream>>>(
            s, v, pay, W_vd, W_vdf, WThi, WTlo, b_so, W_vu, W_vosf, b_vosf, W_vuf,
            head, (const int*)nullptr, out0, out1);
    } else {
        int* nxt = (int*)((char*)d_ws + pay_off);
        bucket_thin_kernel<<<(N_EDGES + 255) / 256, 256, 0, stream>>>(edge_index, head, nxt);
        node_kernel<0><<<N_NODES / NPB, 256, 0, stream>>>(
            s, v, frames, W_vd, W_vdf, WThi, WTlo, b_so, W_vu, W_vosf, b_vosf, W_vuf,
            head, nxt, out0, out1);
    }
}